// Round 1
// baseline (1163.445 us; speedup 1.0000x reference)
//
#include <hip/hip_runtime.h>

// ContractExpand: out[n,b,l,e] = relu(seg_r(x)[b, l/r, :] @ W[n].T + bias[n]) / r
// r = {1,2,4,10,25}, B=64, L=800, D=300.  L % r == 0 for all scales.
// fp32 baseline: fused seg-sum + tiled GEMM + relu/scale + repeat-store.

namespace {
constexpr int D      = 300;
constexpr int BATCH  = 64;
constexpr int LSEQ   = 800;
constexpr int TM     = 32;    // rows (groups) per block
constexpr int KC     = 16;    // K chunk
constexpr int KPAD   = 304;   // 19 * KC, zero-padded K
constexpr int WSTRIDE = 321;  // wt row stride (conflict-free)
constexpr int NCOLS  = 320;   // padded output columns (64 lanes * 5)
}

__global__ __launch_bounds__(256, 2)
void ce_fused(const float* __restrict__ x, const float* __restrict__ W,
              const float* __restrict__ bias, float* __restrict__ out) {
  __shared__ float seg[TM][KPAD];          // 38.9 KB
  __shared__ float wt[KC][WSTRIDE];        // 20.5 KB

  const int bid = blockIdx.x;
  int n, r, g, tile;
  if (bid < 1600)      { n = 0; r = 1;  g = 800; tile = bid;        }
  else if (bid < 2400) { n = 1; r = 2;  g = 400; tile = bid - 1600; }
  else if (bid < 2800) { n = 2; r = 4;  g = 200; tile = bid - 2400; }
  else if (bid < 2960) { n = 3; r = 10; g = 80;  tile = bid - 2800; }
  else                 { n = 4; r = 25; g = 32;  tile = bid - 2960; }

  const int tid = threadIdx.x;
  const int m0  = tile * TM;               // first row within this scale's M = B*g
  const float* __restrict__ Wn = W + (size_t)n * D * D;
  const float* __restrict__ bn = bias + n * D;

  // ---- segment sums into LDS, zero-padded to KPAD ----
  for (int idx = tid; idx < TM * KPAD; idx += 256) {
    const int tm = idx / KPAD;
    const int d  = idx - tm * KPAD;
    float s = 0.f;
    if (d < D) {
      const int m   = m0 + tm;
      const int bb  = m / g;
      const int grp = m - bb * g;
      const float* xp = x + ((size_t)(bb * LSEQ + grp * r)) * D + d;
      for (int j = 0; j < r; ++j) s += xp[(size_t)j * D];
    }
    seg[tm][d] = s;
  }
  __syncthreads();

  const int tx = tid & 63;   // column lane: cols tx + 64*j
  const int ty = tid >> 6;   // row group: rows ty*8 .. ty*8+7

  float acc[8][5];
#pragma unroll
  for (int i = 0; i < 8; ++i)
#pragma unroll
    for (int j = 0; j < 5; ++j) acc[i][j] = 0.f;

  for (int k0 = 0; k0 < KPAD; k0 += KC) {
    // stage W chunk: wt[kk][c] = W[n][c][k0+kk], zero beyond 300
    for (int idx = tid; idx < NCOLS * KC; idx += 256) {
      const int c  = idx >> 4;       // 0..319
      const int kk = idx & 15;
      const int k  = k0 + kk;
      wt[kk][c] = (c < D && k < D) ? Wn[(size_t)c * D + k] : 0.f;
    }
    __syncthreads();

#pragma unroll
    for (int kk = 0; kk < KC; ++kk) {
      float sreg[8];
#pragma unroll
      for (int i = 0; i < 8; ++i) sreg[i] = seg[ty * 8 + i][k0 + kk];  // broadcast
      float wreg[5];
#pragma unroll
      for (int j = 0; j < 5; ++j) wreg[j] = wt[kk][tx + 64 * j];
#pragma unroll
      for (int i = 0; i < 8; ++i)
#pragma unroll
        for (int j = 0; j < 5; ++j) acc[i][j] += sreg[i] * wreg[j];
    }
    __syncthreads();
  }

  // ---- epilogue: bias + relu + /r, repeat each group row r times ----
  float bj[5];
#pragma unroll
  for (int j = 0; j < 5; ++j) {
    const int c = tx + 64 * j;
    bj[j] = (c < D) ? bn[c] : 0.f;
  }
  const float inv_r = 1.f / (float)r;

#pragma unroll
  for (int i = 0; i < 8; ++i) {
    const int m   = m0 + ty * 8 + i;
    const int bb  = m / g;
    const int grp = m - bb * g;
    float y[5];
#pragma unroll
    for (int j = 0; j < 5; ++j) y[j] = fmaxf(acc[i][j] + bj[j], 0.f) * inv_r;

    const size_t lbase = ((size_t)n * BATCH + bb) * LSEQ + (size_t)grp * r;
    for (int q = 0; q < r; ++q) {
      float* __restrict__ op = out + (lbase + q) * D;
#pragma unroll
      for (int j = 0; j < 5; ++j) {
        const int c = tx + 64 * j;
        if (c < D) op[c] = y[j];
      }
    }
  }
}

extern "C" void kernel_launch(void* const* d_in, const int* in_sizes, int n_in,
                              void* d_out, int out_size, void* d_ws, size_t ws_size,
                              hipStream_t stream) {
  const float* x    = (const float*)d_in[0];  // [64, 800, 300]
  const float* W    = (const float*)d_in[1];  // [5, 300, 300]
  const float* bias = (const float*)d_in[2];  // [5, 300]
  float* out        = (float*)d_out;          // [5, 64, 800, 300]

  // 1600 + 800 + 400 + 160 + 64 = 3024 row-tiles of 32 groups each
  ce_fused<<<3024, 256, 0, stream>>>(x, W, bias, out);
}

// Round 2
// 180.496 us; speedup vs baseline: 6.4458x; 6.4458x over previous
//
#include <hip/hip_runtime.h>

// ContractExpand via bf16 MFMA:
//   out[n,b,l,:] = relu(seg_r(x)[b, l/r, :] @ W[n]^T + bias[n]) / r
// r = {25,10,4,2,1} (heavy blocks first), B=64, L=800, D=300.
// Kernel 1: W fp32 -> bf16, padded [5][320][320] (c-major, k contiguous).
// Kernel 2: seg-sum -> LDS bf16 [32][328]; 4 waves x 5 coltiles x 2 mtiles
//           x 10 K-steps of mfma_f32_16x16x32_bf16; fused epilogue with
//           r-way repeated stores.

typedef short bf16x8 __attribute__((ext_vector_type(8)));
typedef float f32x4  __attribute__((ext_vector_type(4)));

namespace {
constexpr int D      = 300;
constexpr int BATCH  = 64;
constexpr int LSEQ   = 800;
constexpr int KP     = 320;   // padded K: 10 steps of 32
constexpr int NP     = 320;   // padded N: 20 tiles of 16 (tile 19 dead)
constexpr int SEGSTR = 328;   // seg LDS row stride (bf16) — 2-way bank alias only
}

__device__ __forceinline__ unsigned short f2bf(float f) {
  unsigned u = __float_as_uint(f);
  u += 0x7fffu + ((u >> 16) & 1u);   // round-to-nearest-even
  return (unsigned short)(u >> 16);
}

__global__ void convert_w(const float* __restrict__ W, short* __restrict__ Wb) {
  int idx = blockIdx.x * 256 + threadIdx.x;
  if (idx >= 5 * NP * KP) return;
  int n   = idx / (NP * KP);
  int rem = idx - n * NP * KP;
  int c = rem / KP, k = rem - c * KP;
  float v = (c < D && k < D) ? W[(size_t)n * D * D + (size_t)c * D + k] : 0.f;
  Wb[idx] = (short)f2bf(v);
}

__global__ __launch_bounds__(256, 4)
void ce_mfma(const float* __restrict__ x, const short* __restrict__ Wb,
             const float* __restrict__ bias, float* __restrict__ out) {
  __shared__ short seg[32 * SEGSTR];   // 20.5 KB

  const int bid = blockIdx.x;
  int n, r, g, tile;
  if (bid < 64)        { n = 4; r = 25; g = 32;  tile = bid;        }
  else if (bid < 224)  { n = 3; r = 10; g = 80;  tile = bid - 64;   }
  else if (bid < 624)  { n = 2; r = 4;  g = 200; tile = bid - 224;  }
  else if (bid < 1424) { n = 1; r = 2;  g = 400; tile = bid - 624;  }
  else                 { n = 0; r = 1;  g = 800; tile = bid - 1424; }

  const int tid = threadIdx.x;
  const int m0  = tile * 32;           // first row in this scale's M = 64*g

  // ---- phase 1: segment sums (fp32) -> bf16 LDS tile [32][KP], zero-padded ----
  #pragma unroll
  for (int it = 0; it < 5; ++it) {
    const int cidx = tid + it * 256;       // 0..1279 = 32 rows x 40 chunks
    const int row  = cidx / 40;
    const int kc   = (cidx - row * 40) * 8;
    float s[8];
    #pragma unroll
    for (int j = 0; j < 8; ++j) s[j] = 0.f;
    if (kc < D) {
      const int m   = m0 + row;
      const int bb  = m / g;
      const int grp = m - bb * g;
      const float* xp = x + ((size_t)(bb * LSEQ + grp * r)) * D + kc;
      if (kc <= D - 8) {
        for (int q = 0; q < r; ++q) {
          const float4 v0 = *(const float4*)(xp + (size_t)q * D);
          const float4 v1 = *(const float4*)(xp + (size_t)q * D + 4);
          s[0] += v0.x; s[1] += v0.y; s[2] += v0.z; s[3] += v0.w;
          s[4] += v1.x; s[5] += v1.y; s[6] += v1.z; s[7] += v1.w;
        }
      } else {
        for (int q = 0; q < r; ++q) {
          #pragma unroll
          for (int j = 0; j < 8; ++j)
            if (kc + j < D) s[j] += xp[(size_t)q * D + j];
        }
      }
    }
    bf16x8 p;
    #pragma unroll
    for (int j = 0; j < 8; ++j) p[j] = (short)f2bf(s[j]);
    *(bf16x8*)(&seg[row * SEGSTR + kc]) = p;
  }
  __syncthreads();

  // ---- phase 2: MFMA GEMM.  A = seg (16x32 frags from LDS), B = W^T (global bf16) ----
  const int wv   = tid >> 6;
  const int lane = tid & 63;
  const int cr   = lane & 15;    // A: row, B: col, C: col
  const int kh   = lane >> 4;    // k-half index (0..3) -> k = kh*8 + j

  f32x4 acc[2][5];
  #pragma unroll
  for (int mt = 0; mt < 2; ++mt)
    #pragma unroll
    for (int t = 0; t < 5; ++t) acc[mt][t] = (f32x4){0.f, 0.f, 0.f, 0.f};

  const short* __restrict__ Wn = Wb + (size_t)n * NP * KP;
  const int a0_off = cr * SEGSTR + kh * 8;
  const int a1_off = (16 + cr) * SEGSTR + kh * 8;

  #pragma unroll
  for (int ks = 0; ks < 10; ++ks) {
    const int k0 = ks * 32;
    const bf16x8 a0 = *(const bf16x8*)(&seg[a0_off + k0]);
    const bf16x8 a1 = *(const bf16x8*)(&seg[a1_off + k0]);
    bf16x8 bfr[5];
    #pragma unroll
    for (int t = 0; t < 5; ++t) {
      const int c = (wv * 5 + t) * 16 + cr;
      bfr[t] = *(const bf16x8*)(Wn + (size_t)c * KP + k0 + kh * 8);
    }
    #pragma unroll
    for (int t = 0; t < 5; ++t) {
      acc[0][t] = __builtin_amdgcn_mfma_f32_16x16x32_bf16(a0, bfr[t], acc[0][t], 0, 0, 0);
      acc[1][t] = __builtin_amdgcn_mfma_f32_16x16x32_bf16(a1, bfr[t], acc[1][t], 0, 0, 0);
    }
  }

  // ---- epilogue: bias + relu + /r, repeat each group row r times ----
  const float inv_r = 1.f / (float)r;
  const float* __restrict__ bn = bias + n * D;
  float bv[5];
  int cols[5];
  #pragma unroll
  for (int t = 0; t < 5; ++t) {
    const int c = (wv * 5 + t) * 16 + cr;
    cols[t] = c;
    bv[t]   = (c < D) ? bn[c] : 0.f;
  }

  #pragma unroll
  for (int mt = 0; mt < 2; ++mt) {
    #pragma unroll
    for (int j = 0; j < 4; ++j) {
      const int row = mt * 16 + kh * 4 + j;   // C/D: row = (lane>>4)*4 + reg
      const int m   = m0 + row;
      const int bb  = m / g;
      const int grp = m - bb * g;
      const size_t base = ((size_t)(n * BATCH + bb) * LSEQ + (size_t)grp * r) * D;
      #pragma unroll
      for (int t = 0; t < 5; ++t) {
        if (cols[t] < D) {
          const float y = fmaxf(acc[mt][t][j] + bv[t], 0.f) * inv_r;
          float* __restrict__ op = out + base + cols[t];
          for (int q = 0; q < r; ++q) op[(size_t)q * D] = y;
        }
      }
    }
  }
}

extern "C" void kernel_launch(void* const* d_in, const int* in_sizes, int n_in,
                              void* d_out, int out_size, void* d_ws, size_t ws_size,
                              hipStream_t stream) {
  const float* x    = (const float*)d_in[0];  // [64, 800, 300]
  const float* W    = (const float*)d_in[1];  // [5, 300, 300]
  const float* bias = (const float*)d_in[2];  // [5, 300]
  float* out        = (float*)d_out;          // [5, 64, 800, 300]
  short* Wb         = (short*)d_ws;           // [5][320][320] bf16, ~1 MB

  convert_w<<<(5 * NP * KP + 255) / 256, 256, 0, stream>>>(W, Wb);
  ce_mfma<<<3024, 256, 0, stream>>>(x, Wb, bias, out);
}